// Round 1
// 1172.639 us; speedup vs baseline: 1.1667x; 1.1667x over previous
//
#include <hip/hip_runtime.h>
#include <hip/hip_bf16.h>

typedef __bf16 bf16_t;
typedef __bf16 bf16x8 __attribute__((ext_vector_type(8)));
typedef float f32x4 __attribute__((ext_vector_type(4)));

// stage 8 fp32 elements -> 8 bf16 in LDS (RNE via compiler fptrunc)
__device__ inline void stage8(const float* __restrict__ src, bf16_t* __restrict__ dst) {
    float4 u = *(const float4*)src;
    float4 v = *(const float4*)(src + 4);
    bf16x8 t;
    t[0] = (bf16_t)u.x; t[1] = (bf16_t)u.y; t[2] = (bf16_t)u.z; t[3] = (bf16_t)u.w;
    t[4] = (bf16_t)v.x; t[5] = (bf16_t)v.y; t[6] = (bf16_t)v.z; t[7] = (bf16_t)v.w;
    *(bf16x8*)dst = t;
}

// async global->LDS, 16B per lane. ldsbase must be wave-uniform; HW writes ldsbase + lane*16.
__device__ inline void gload_lds16(const bf16_t* g, bf16_t* l) {
    __builtin_amdgcn_global_load_lds(
        (const __attribute__((address_space(1))) unsigned int*)g,
        (__attribute__((address_space(3))) unsigned int*)l,
        16, 0, 0);
}

// ---------------- mean over S + h fp32->bf16 conversion (fused: h is read once anyway) ----
__global__ void mean_kernel(const float* __restrict__ h, bf16_t* __restrict__ havg,
                            bf16_t* __restrict__ h_bf) {
    int idx = blockIdx.x * 256 + threadIdx.x;      // 65536 = B*E
    float s = 0.f;
    for (int si = 0; si < 196; si++) {
        float v = h[(size_t)si * 65536 + idx];
        h_bf[(size_t)si * 65536 + idx] = (bf16_t)v;
        s += v;
    }
    havg[idx] = (bf16_t)(s * (1.f / 196.f));
}

// ---------------- Wa1 key-slice -> bf16 [1920,1024] (zero-padded rows); wa2 padded ----
__global__ void conv_wa1(const float* __restrict__ Wa1, const float* __restrict__ Wa2,
                         bf16_t* __restrict__ Wa1bf, float* __restrict__ wa2p) {
    int idx = blockIdx.x * 256 + threadIdx.x;   // over 1920*1024
    int nrow = idx >> 10, k = idx & 1023;
    Wa1bf[idx] = (nrow < 1800) ? (bf16_t)Wa1[(size_t)nrow * 2824 + 1800 + k] : (bf16_t)0.f;
    if (idx < 1920) wa2p[idx] = (idx < 1800) ? Wa2[idx] : 0.f;
}

// ---------------- argmax over V per row (first-index tie-break) ----------------
__global__ __launch_bounds__(256) void argmax_kernel(const float* __restrict__ y, int* __restrict__ idx_out) {
    int b = blockIdx.x;
    const float* row = y + (size_t)b * 32000;
    float best = -1e30f; int bi = 0x7fffffff;
    for (int v = threadIdx.x; v < 32000; v += 256) {
        float val = row[v];
        if (val > best) { best = val; bi = v; }
    }
    __shared__ float bv[256]; __shared__ int bidx[256];
    bv[threadIdx.x] = best; bidx[threadIdx.x] = bi;
    __syncthreads();
    for (int s = 128; s > 0; s >>= 1) {
        if (threadIdx.x < s) {
            float ov = bv[threadIdx.x + s]; int oi = bidx[threadIdx.x + s];
            if (ov > bv[threadIdx.x] || (ov == bv[threadIdx.x] && oi < bidx[threadIdx.x])) {
                bv[threadIdx.x] = ov; bidx[threadIdx.x] = oi;
            }
        }
        __syncthreads();
    }
    if (threadIdx.x == 0) idx_out[b] = bidx[0];
}

// ---------------- generic M=64 GEMM: C = A[64,K](bf16) @ W[N,K](fp32)^T ----------------
__global__ __launch_bounds__(256) void gemm64(
    const bf16_t* __restrict__ A, int lda, int K,
    const float* __restrict__ W, int ldw,
    const float* __restrict__ bias,
    const float* __restrict__ Cadd,
    float* __restrict__ Cf, bf16_t* __restrict__ Cbf, int ldc,
    int N, int act)
{
    __shared__ __align__(16) bf16_t aA[64 * 32];
    __shared__ __align__(16) bf16_t wB[64 * 32];
    int tid = threadIdx.x, wave = tid >> 6, lane = tid & 63;
    int n0 = blockIdx.x * 64;
    int chunks = (K + 31) >> 5;
    int cs = (int)(((long)chunks * blockIdx.y) / gridDim.y);
    int ce = (int)(((long)chunks * (blockIdx.y + 1)) / gridDim.y);
    int kstart = cs * 32, kend = min(K, ce * 32);
    if (gridDim.y > 1) Cf += (size_t)blockIdx.y * 64 * ldc;
    f32x4 acc[4] = {};
    int arow = tid >> 2, acol = (tid & 3) * 8;
    int nrow = n0 + arow;
    for (int k0 = kstart; k0 < kend; k0 += 32) {
        int k = k0 + acol;
        if (k + 8 <= K) {
            *(float4*)(&aA[arow * 32 + acol]) = *(const float4*)(&A[(size_t)arow * lda + k]);
        } else {
            for (int i = 0; i < 8; i++) aA[arow * 32 + acol + i] = (k + i < K) ? A[(size_t)arow * lda + k + i] : (bf16_t)0.f;
        }
        if (nrow < N) {
            if (k + 8 <= K) {
                stage8(&W[(size_t)nrow * ldw + k], &wB[arow * 32 + acol]);
            } else {
                for (int i = 0; i < 8; i++) wB[arow * 32 + acol + i] = (k + i < K) ? (bf16_t)W[(size_t)nrow * ldw + k + i] : (bf16_t)0.f;
            }
        } else {
            *(float4*)(&wB[arow * 32 + acol]) = make_float4(0.f, 0.f, 0.f, 0.f);
        }
        __syncthreads();
        bf16x8 af = *(const bf16x8*)(&aA[(16 * wave + (lane & 15)) * 32 + (lane >> 4) * 8]);
#pragma unroll
        for (int j = 0; j < 4; j++) {
            bf16x8 bfr = *(const bf16x8*)(&wB[(16 * j + (lane & 15)) * 32 + (lane >> 4) * 8]);
            acc[j] = __builtin_amdgcn_mfma_f32_16x16x32_bf16(af, bfr, acc[j], 0, 0, 0);
        }
        __syncthreads();
    }
    int mbase = 16 * wave + (lane >> 4) * 4;
    int ncol = lane & 15;
#pragma unroll
    for (int j = 0; j < 4; j++) {
        int n = n0 + 16 * j + ncol;
        if (n >= N) continue;
        float bv = bias ? bias[n] : 0.f;
#pragma unroll
        for (int rg = 0; rg < 4; rg++) {
            int m = mbase + rg;
            float v = acc[j][rg] + bv;
            if (Cadd) v += Cadd[(size_t)m * ldc + n];
            if (act) v = fmaxf(v, 0.f);
            if (Cf) Cf[(size_t)m * ldc + n] = v;
            if (Cbf) Cbf[(size_t)m * ldc + n] = (bf16_t)v;
        }
    }
}

// ---------------- finalize split-K partials: sum KS slices + bias + act ----------------
__global__ void gemm_finalize(const float* __restrict__ part, int KS,
                              const float* __restrict__ bias, int act,
                              float* __restrict__ Cf, bf16_t* __restrict__ Cbf, int N) {
    int idx = blockIdx.x * 256 + threadIdx.x;    // over 64*N
    if (idx >= 64 * N) return;
    int m = idx / N, n = idx - m * N;
    float s = 0.f;
    for (int k = 0; k < KS; k++) s += part[(size_t)(k * 64 + m) * N + n];
    if (bias) s += bias[n];
    if (act) s = fmaxf(s, 0.f);
    if (Cf) Cf[idx] = s;
    if (Cbf) Cbf[idx] = (bf16_t)s;
}

// ---------------- fused attention scores as a real 128x128-tile GEMM ----------------
// U = A[12544,1024] @ Bw[1920,1024]^T ; scores_m += sum_n relu(U[m,n] + r[m&63,n]) * wa2p[n]
// grid (98, 15): x = m-tile, y = n-tile. 30 partial slices: [y*2 + wave&1][12544].
__global__ __launch_bounds__(256) void attn_gemm(
    const bf16_t* __restrict__ A, const bf16_t* __restrict__ Bw,
    const float* __restrict__ r, const float* __restrict__ wa2p,
    float* __restrict__ scoresP)
{
    __shared__ __align__(16) bf16_t aA[128 * 32];
    __shared__ __align__(16) bf16_t wB[128 * 32];
    int tid = threadIdx.x, wave = tid >> 6, lane = tid & 63;
    int m0 = blockIdx.x * 128, n0 = blockIdx.y * 128;
    // staging: lane covers row = wave*32 + (lane>>2) (+16 for 2nd issue), col8 = (lane&3)*8
    int srow = lane >> 2, scol = (lane & 3) * 8;
    const bf16_t* Ag = A + (size_t)(m0 + wave * 32 + srow) * 1024 + scol;
    const bf16_t* Bg = Bw + (size_t)(n0 + wave * 32 + srow) * 1024 + scol;
    bf16_t* aL0 = &aA[wave * 1024];        // wave-uniform LDS bases (lane*16B implicit)
    bf16_t* aL1 = &aA[wave * 1024 + 512];
    bf16_t* bL0 = &wB[wave * 1024];
    bf16_t* bL1 = &wB[wave * 1024 + 512];
    int mw = (wave >> 1) * 64, nw = (wave & 1) * 64;
    f32x4 acc[4][4] = {};
    for (int k0 = 0; k0 < 1024; k0 += 32) {
        gload_lds16(Ag + k0, aL0);
        gload_lds16(Ag + 16 * 1024 + k0, aL1);
        gload_lds16(Bg + k0, bL0);
        gload_lds16(Bg + 16 * 1024 + k0, bL1);
        __syncthreads();                     // compiler drains vmcnt before barrier
        bf16x8 af[4], bfr[4];
#pragma unroll
        for (int i = 0; i < 4; i++) {
            af[i]  = *(const bf16x8*)(&aA[(mw + i * 16 + (lane & 15)) * 32 + (lane >> 4) * 8]);
            bfr[i] = *(const bf16x8*)(&wB[(nw + i * 16 + (lane & 15)) * 32 + (lane >> 4) * 8]);
        }
#pragma unroll
        for (int mi = 0; mi < 4; mi++)
#pragma unroll
            for (int nj = 0; nj < 4; nj++)
                acc[mi][nj] = __builtin_amdgcn_mfma_f32_16x16x32_bf16(af[mi], bfr[nj], acc[mi][nj], 0, 0, 0);
        __syncthreads();
    }
    // epilogue: relu(acc + r) * wa2, reduce over this wave's 64 columns
    int ncol = lane & 15;
    int part = blockIdx.y * 2 + (wave & 1);
    float w2[4];
#pragma unroll
    for (int nj = 0; nj < 4; nj++) w2[nj] = wa2p[n0 + nw + nj * 16 + ncol];
#pragma unroll
    for (int mi = 0; mi < 4; mi++) {
#pragma unroll
        for (int rg = 0; rg < 4; rg++) {
            int m = m0 + mw + mi * 16 + (lane >> 4) * 4 + rg;
            const float* rrow = r + (size_t)(m & 63) * 1800;
            float s = 0.f;
#pragma unroll
            for (int nj = 0; nj < 4; nj++) {
                int n = n0 + nw + nj * 16 + ncol;
                float rv = (n < 1800) ? rrow[n] : 0.f;   // pad cols: wa2p==0 kills them
                s += fmaxf(acc[mi][nj][rg] + rv, 0.f) * w2[nj];
            }
#pragma unroll
            for (int d = 1; d < 16; d <<= 1) s += __shfl_xor(s, d, 64);
            if (ncol == 0) scoresP[(size_t)part * 12544 + m] = s;
        }
    }
}

// ---------------- softmax over S (per b) + beta gate ----------------
__global__ __launch_bounds__(256) void softmax_beta(
    const float* __restrict__ scoresP, float* __restrict__ aw32,
    float* __restrict__ aw_out, const bf16_t* __restrict__ h0,
    const float* __restrict__ Wb, const float* __restrict__ bb,
    const float* __restrict__ ba2, float* __restrict__ beta)
{
    int b = blockIdx.x, t = threadIdx.x;
    __shared__ float red[4];
    __shared__ float bc;
    float v = -1e30f;
    if (t < 196) {
        float s = ba2[0];
        for (int p = 0; p < 30; p++) s += scoresP[(size_t)p * 12544 + t * 64 + b];
        v = s;
    }
    float m = v;
    for (int d = 1; d < 64; d <<= 1) m = fmaxf(m, __shfl_xor(m, d, 64));
    if ((t & 63) == 0) red[t >> 6] = m;
    __syncthreads();
    if (t == 0) bc = fmaxf(fmaxf(red[0], red[1]), fmaxf(red[2], red[3]));
    __syncthreads();
    m = bc;
    float e = (t < 196) ? expf(v - m) : 0.f;
    float s = e;
    for (int d = 1; d < 64; d <<= 1) s += __shfl_xor(s, d, 64);
    __syncthreads();
    if ((t & 63) == 0) red[t >> 6] = s;
    __syncthreads();
    if (t == 0) bc = red[0] + red[1] + red[2] + red[3];
    __syncthreads();
    float inv = 1.f / bc;
    if (t < 196) { float a = e * inv; aw32[t * 64 + b] = a; aw_out[t * 64 + b] = a; }
    // beta[b] = sigmoid(h0[b,:] . Wb + bb)
    float bs = 0.f;
    for (int k = t; k < 1800; k += 256) bs += (float)h0[b * 1800 + k] * Wb[k];
    for (int d = 1; d < 64; d <<= 1) bs += __shfl_xor(bs, d, 64);
    __syncthreads();
    if ((t & 63) == 0) red[t >> 6] = bs;
    __syncthreads();
    if (t == 0) beta[b] = 1.f / (1.f + expf(-(red[0] + red[1] + red[2] + red[3] + bb[0])));
}

// ---------------- ctx = (sum_s aw*h) * beta -> xA[:,512:], zA[:,2312:] ----------------
__global__ void ctx_kernel(const float* __restrict__ h, const float* __restrict__ aw32,
                           const float* __restrict__ beta, bf16_t* __restrict__ xA, bf16_t* __restrict__ zA) {
    int idx = blockIdx.x * 256 + threadIdx.x;    // 65536 = B*E
    int b = idx >> 10, e = idx & 1023;
    float s = 0.f;
    for (int si = 0; si < 196; si++) s += aw32[si * 64 + b] * h[(size_t)si * 65536 + idx];
    float c = s * beta[b];
    xA[b * 1536 + 512 + e] = (bf16_t)c;
    zA[b * 3336 + 2312 + e] = (bf16_t)c;
}

// ---------------- gathers: emb[E_tm1] -> xA[:,0:512]; emb[argmax] -> zA[:,1800:2312] ----------------
__global__ void gather_kernel(const float* __restrict__ emb, const int* __restrict__ E_tm1,
                              const int* __restrict__ amax, bf16_t* __restrict__ xA, bf16_t* __restrict__ zA) {
    int idx = blockIdx.x * 256 + threadIdx.x;    // 65536 = 2*64*512
    int half = idx >> 15;
    int j = idx & 32767; int b = j >> 9, w = j & 511;
    if (half == 0) xA[b * 1536 + w] = (bf16_t)emb[(size_t)E_tm1[b] * 512 + w];
    else           zA[b * 3336 + 1800 + w] = (bf16_t)emb[(size_t)amax[b] * 512 + w];
}

// ---------------- LSTM elementwise ----------------
__global__ void lstm_kernel(const float* __restrict__ gates, const float* __restrict__ c0,
                            float* __restrict__ oh, float* __restrict__ oc, bf16_t* __restrict__ zA) {
    int idx = blockIdx.x * 256 + threadIdx.x;    // 115200 = B*D
    if (idx >= 115200) return;
    int b = idx / 1800, d = idx - b * 1800;
    const float* g = gates + (size_t)b * 7200;
    float ig = 1.f / (1.f + expf(-g[d]));
    float fg = 1.f / (1.f + expf(-g[1800 + d]));
    float gg = tanhf(g[3600 + d]);
    float og = 1.f / (1.f + expf(-g[5400 + d]));
    float ct = fg * c0[idx] + ig * gg;
    float ht = og * tanhf(ct);
    oh[idx] = ht;
    oc[idx] = ct;
    zA[b * 3336 + d] = (bf16_t)ht;
}

extern "C" void kernel_launch(void* const* d_in, const int* in_sizes, int n_in,
                              void* d_out, int out_size, void* d_ws, size_t ws_size,
                              hipStream_t stream) {
    const int*   E_tm1 = (const int*)d_in[0];
    const float* y_tm1 = (const float*)d_in[1];
    const float* h     = (const float*)d_in[2];
    const float* emb   = (const float*)d_in[3];
    const float* W_ih  = (const float*)d_in[4];
    const float* b_ih  = (const float*)d_in[5];
    const float* W_hh  = (const float*)d_in[6];
    const float* b_hh  = (const float*)d_in[7];
    const float* W_out = (const float*)d_in[8];
    const float* b_out = (const float*)d_in[9];
    const float* Wh1   = (const float*)d_in[10];
    const float* bh1   = (const float*)d_in[11];
    const float* Wh2   = (const float*)d_in[12];
    const float* bh2   = (const float*)d_in[13];
    const float* Wc1   = (const float*)d_in[14];
    const float* bc1   = (const float*)d_in[15];
    const float* Wc2   = (const float*)d_in[16];
    const float* bc2   = (const float*)d_in[17];
    const float* Wa1   = (const float*)d_in[18];
    const float* ba1   = (const float*)d_in[19];
    const float* Wa2   = (const float*)d_in[20];
    const float* ba2   = (const float*)d_in[21];
    const float* Wb    = (const float*)d_in[22];
    const float* bb    = (const float*)d_in[23];

    // workspace layout (fp32 elements); 'part' is reused as 'gates'
    float* wsf     = (float*)d_ws;
    float* part    = wsf;                    // 460800 (split-K partials, then gates)
    float* gates   = part;
    float* r_buf   = wsf + 460800;           // 115200
    float* scoresP = wsf + 576000;           // 376320 ([30][12544])
    float* aw32    = wsf + 952320;           // 12544
    float* beta    = wsf + 964864;           // 64
    float* c0      = wsf + 964928;           // 115200
    float* wa2p    = wsf + 1080128;          // 1920
    int*   amax    = (int*)(wsf + 1082048);  // 64
    bf16_t* havg = (bf16_t*)(wsf + 1082112); // 65536 bf16
    bf16_t* t1   = havg + 65536;             // 115200
    bf16_t* t2   = t1 + 115200;              // 115200
    bf16_t* h0   = t2 + 115200;              // 115200
    bf16_t* xA   = h0 + 115200;              // 64*1536
    bf16_t* zA   = xA + 98304;               // 64*3336 = 213504
    bf16_t* h_bf = zA + 213504;              // 196*64*1024 = 12845056
    bf16_t* Wa1bf= h_bf + 12845056;          // 1920*1024 = 1966080

    float* out        = (float*)d_out;
    float* out_logits = out;                 // 64*32000
    float* out_ht     = out + 2048000;       // 64*1800
    float* out_ct     = out + 2163200;       // 64*1800
    float* out_aw     = out + 2278400;       // 196*64

    mean_kernel<<<256, 256, 0, stream>>>(h, havg, h_bf);
    conv_wa1<<<7680, 256, 0, stream>>>(Wa1, Wa2, Wa1bf, wa2p);
    argmax_kernel<<<64, 256, 0, stream>>>(y_tm1, amax);

    // t1 = relu(havg @ Wh1^T + bh1)
    gemm64<<<dim3(29, 4), 256, 0, stream>>>(havg, 1024, 1024, Wh1, 1024, nullptr, nullptr, part, nullptr, 1800, 1800, 0);
    gemm_finalize<<<450, 256, 0, stream>>>(part, 4, bh1, 1, nullptr, t1, 1800);
    // t2 = relu(havg @ Wc1^T + bc1)
    gemm64<<<dim3(29, 4), 256, 0, stream>>>(havg, 1024, 1024, Wc1, 1024, nullptr, nullptr, part, nullptr, 1800, 1800, 0);
    gemm_finalize<<<450, 256, 0, stream>>>(part, 4, bc1, 1, nullptr, t2, 1800);
    // h0 = t1 @ Wh2^T + bh2
    gemm64<<<dim3(29, 4), 256, 0, stream>>>(t1, 1800, 1800, Wh2, 1800, nullptr, nullptr, part, nullptr, 1800, 1800, 0);
    gemm_finalize<<<450, 256, 0, stream>>>(part, 4, bh2, 0, nullptr, h0, 1800);
    // c0 = t2 @ Wc2^T + bc2
    gemm64<<<dim3(29, 4), 256, 0, stream>>>(t2, 1800, 1800, Wc2, 1800, nullptr, nullptr, part, nullptr, 1800, 1800, 0);
    gemm_finalize<<<450, 256, 0, stream>>>(part, 4, bc2, 0, c0, nullptr, 1800);
    // r = h0 @ Wa1[:, :1800]^T + ba1   (query part of additive attention, hoisted out of S)
    gemm64<<<dim3(29, 4), 256, 0, stream>>>(h0, 1800, 1800, Wa1, 2824, nullptr, nullptr, part, nullptr, 1800, 1800, 0);
    gemm_finalize<<<450, 256, 0, stream>>>(part, 4, ba1, 0, r_buf, nullptr, 1800);

    // fused attention scores: real 128x128-tile GEMM over M=12544, N=1920(pad), K=1024
    attn_gemm<<<dim3(98, 15), 256, 0, stream>>>(h_bf, Wa1bf, r_buf, wa2p, scoresP);
    softmax_beta<<<64, 256, 0, stream>>>(scoresP, aw32, out_aw, h0, Wb, bb, ba2, beta);
    ctx_kernel<<<256, 256, 0, stream>>>(h, aw32, beta, xA, zA);
    gather_kernel<<<256, 256, 0, stream>>>(emb, E_tm1, amax, xA, zA);

    // LSTM gates (gates aliases part — all split-K GEMMs are done by now)
    gemm64<<<dim3(113, 1), 256, 0, stream>>>(xA, 1536, 1536, W_ih, 1536, b_ih, nullptr, gates, nullptr, 7200, 7200, 0);
    gemm64<<<dim3(113, 1), 256, 0, stream>>>(h0, 1800, 1800, W_hh, 1800, b_hh, gates, gates, nullptr, 7200, 7200, 0);
    lstm_kernel<<<450, 256, 0, stream>>>(gates, c0, out_ht, out_ct, zA);

    // logits = zA @ W_out^T + b_out  (memory-bound: 427 MB of fp32 W_out; fp32 out via Cf)
    gemm64<<<dim3(500, 1), 256, 0, stream>>>(zA, 3336, 3336, W_out, 3336, b_out, nullptr, out_logits, nullptr, 32000, 32000, 0);
}

// Round 2
// 1057.957 us; speedup vs baseline: 1.2932x; 1.1084x over previous
//
#include <hip/hip_runtime.h>
#include <hip/hip_bf16.h>

typedef __bf16 bf16_t;
typedef __bf16 bf16x8 __attribute__((ext_vector_type(8)));
typedef float f32x4 __attribute__((ext_vector_type(4)));

__device__ inline bf16x8 zero8() {
    bf16x8 t;
#pragma unroll
    for (int i = 0; i < 8; i++) t[i] = (bf16_t)0.f;
    return t;
}

// load 8 fp32 of W[row, k..k+8) -> bf16x8 (RNE), zero-padded past K
__device__ inline bf16x8 loadW8(const float* __restrict__ W, size_t row, int k, int K, int ldw) {
    bf16x8 t;
    if (k + 8 <= K) {
        float4 u = *(const float4*)(W + row * ldw + k);
        float4 v = *(const float4*)(W + row * ldw + k + 4);
        t[0] = (bf16_t)u.x; t[1] = (bf16_t)u.y; t[2] = (bf16_t)u.z; t[3] = (bf16_t)u.w;
        t[4] = (bf16_t)v.x; t[5] = (bf16_t)v.y; t[6] = (bf16_t)v.z; t[7] = (bf16_t)v.w;
    } else {
#pragma unroll
        for (int i = 0; i < 8; i++) t[i] = (k + i < K) ? (bf16_t)W[row * ldw + k + i] : (bf16_t)0.f;
    }
    return t;
}

// load 8 bf16 of A[row, k..k+8), zero-padded past K
__device__ inline bf16x8 loadA8(const bf16_t* __restrict__ A, size_t row, int k, int K, int lda) {
    if (k + 8 <= K) return *(const bf16x8*)(A + row * lda + k);
    bf16x8 t;
#pragma unroll
    for (int i = 0; i < 8; i++) t[i] = (k + i < K) ? A[row * lda + k + i] : (bf16_t)0.f;
    return t;
}

// async global->LDS, 16B per lane. ldsbase must be wave-uniform; HW writes ldsbase + lane*16.
__device__ inline void gload_lds16(const bf16_t* g, bf16_t* l) {
    __builtin_amdgcn_global_load_lds(
        (const __attribute__((address_space(1))) unsigned int*)g,
        (__attribute__((address_space(3))) unsigned int*)l,
        16, 0, 0);
}

// ---------------- mean over S + h fp32->bf16 conversion (fused: h is read once anyway) ----
__global__ void mean_kernel(const float* __restrict__ h, bf16_t* __restrict__ havg,
                            bf16_t* __restrict__ h_bf) {
    int idx = blockIdx.x * 256 + threadIdx.x;      // 65536 = B*E
    float s = 0.f;
    for (int si = 0; si < 196; si++) {
        float v = h[(size_t)si * 65536 + idx];
        h_bf[(size_t)si * 65536 + idx] = (bf16_t)v;
        s += v;
    }
    havg[idx] = (bf16_t)(s * (1.f / 196.f));
}

// ---------------- Wa1 key-slice -> bf16 [1920,1024] (zero-padded rows); wa2 padded ----
__global__ void conv_wa1(const float* __restrict__ Wa1, const float* __restrict__ Wa2,
                         bf16_t* __restrict__ Wa1bf, float* __restrict__ wa2p) {
    int idx = blockIdx.x * 256 + threadIdx.x;   // over 1920*1024
    int nrow = idx >> 10, k = idx & 1023;
    Wa1bf[idx] = (nrow < 1800) ? (bf16_t)Wa1[(size_t)nrow * 2824 + 1800 + k] : (bf16_t)0.f;
    if (idx < 1920) wa2p[idx] = (idx < 1800) ? Wa2[idx] : 0.f;
}

// ---------------- argmax over V per row (first-index tie-break) ----------------
__global__ __launch_bounds__(256) void argmax_kernel(const float* __restrict__ y, int* __restrict__ idx_out) {
    int b = blockIdx.x;
    const float* row = y + (size_t)b * 32000;
    float best = -1e30f; int bi = 0x7fffffff;
    for (int v = threadIdx.x; v < 32000; v += 256) {
        float val = row[v];
        if (val > best) { best = val; bi = v; }
    }
    __shared__ float bv[256]; __shared__ int bidx[256];
    bv[threadIdx.x] = best; bidx[threadIdx.x] = bi;
    __syncthreads();
    for (int s = 128; s > 0; s >>= 1) {
        if (threadIdx.x < s) {
            float ov = bv[threadIdx.x + s]; int oi = bidx[threadIdx.x + s];
            if (ov > bv[threadIdx.x] || (ov == bv[threadIdx.x] && oi < bidx[threadIdx.x])) {
                bv[threadIdx.x] = ov; bidx[threadIdx.x] = oi;
            }
        }
        __syncthreads();
    }
    if (threadIdx.x == 0) idx_out[b] = bidx[0];
}

// ---------------- M=64 GEMM v2: partials = A[64,K](bf16) @ W[N,K](fp32)^T ----------------
// Double-buffered LDS (1 barrier/chunk) + register prefetch of next chunk.
// grid.x = ceil(N/64); grid.y = KS. Pf is [KS][64][ldc] fp32 partials (no bias/act).
__global__ __launch_bounds__(256) void gemm64v2(
    const bf16_t* __restrict__ A, int lda, int K,
    const float* __restrict__ W, int ldw,
    float* __restrict__ Pf, int ldc, int N)
{
    __shared__ __align__(16) bf16_t aA[2][64 * 32];
    __shared__ __align__(16) bf16_t wB[2][64 * 32];
    int tid = threadIdx.x, wave = tid >> 6, lane = tid & 63;
    int n0 = blockIdx.x * 64;
    int chunks = (K + 31) >> 5;
    int cs = (int)(((long)chunks * blockIdx.y) / gridDim.y);
    int ce = (int)(((long)chunks * (blockIdx.y + 1)) / gridDim.y);
    int kstart = cs * 32, kend = min(K, ce * 32);
    Pf += (size_t)blockIdx.y * 64 * ldc;
    int arow = tid >> 2, acol = (tid & 3) * 8;
    int nrow = n0 + arow;
    bool wvalid = nrow < N;
    f32x4 acc[4] = {};
    bf16x8 aR = zero8(), wR = zero8();
    if (kstart < kend) {
        aR = loadA8(A, (size_t)arow, kstart + acol, K, lda);
        if (wvalid) wR = loadW8(W, (size_t)nrow, kstart + acol, K, ldw);
    }
    int buf = 0;
    for (int k0 = kstart; k0 < kend; k0 += 32) {
        *(bf16x8*)(&aA[buf][arow * 32 + acol]) = aR;
        *(bf16x8*)(&wB[buf][arow * 32 + acol]) = wR;
        __syncthreads();
        int kn = k0 + 32;
        if (kn < kend) {                       // prefetch next chunk (overlaps MFMA below)
            aR = loadA8(A, (size_t)arow, kn + acol, K, lda);
            if (wvalid) wR = loadW8(W, (size_t)nrow, kn + acol, K, ldw);
        }
        bf16x8 af = *(const bf16x8*)(&aA[buf][(16 * wave + (lane & 15)) * 32 + (lane >> 4) * 8]);
#pragma unroll
        for (int j = 0; j < 4; j++) {
            bf16x8 bfr = *(const bf16x8*)(&wB[buf][(16 * j + (lane & 15)) * 32 + (lane >> 4) * 8]);
            acc[j] = __builtin_amdgcn_mfma_f32_16x16x32_bf16(af, bfr, acc[j], 0, 0, 0);
        }
        buf ^= 1;
    }
    int mbase = 16 * wave + (lane >> 4) * 4;
    int ncol = lane & 15;
#pragma unroll
    for (int j = 0; j < 4; j++) {
        int n = n0 + 16 * j + ncol;
        if (n >= N) continue;
#pragma unroll
        for (int rg = 0; rg < 4; rg++)
            Pf[(size_t)(mbase + rg) * ldc + n] = acc[j][rg];
    }
}

// ---------------- finalize split-K partials: sum KS slices + bias + act ----------------
__global__ void gemm_finalize(const float* __restrict__ part, int KS,
                              const float* __restrict__ bias, int act,
                              float* __restrict__ Cf, bf16_t* __restrict__ Cbf, int N) {
    int idx = blockIdx.x * 256 + threadIdx.x;    // over 64*N
    if (idx >= 64 * N) return;
    int m = idx / N, n = idx - m * N;
    float s = 0.f;
    for (int k = 0; k < KS; k++) s += part[(size_t)(k * 64 + m) * N + n];
    if (bias) s += bias[n];
    if (act) s = fmaxf(s, 0.f);
    if (Cf) Cf[idx] = s;
    if (Cbf) Cbf[idx] = (bf16_t)s;
}

// ---------------- fused attention scores as a real 128x128-tile GEMM ----------------
// U = A[12544,1024] @ Bw[1920,1024]^T ; scores_m += sum_n relu(U[m,n] + r[m&63,n]) * wa2p[n]
// grid (98, 15): x = m-tile, y = n-tile. 30 partial slices: [y*2 + wave&1][12544].
__global__ __launch_bounds__(256) void attn_gemm(
    const bf16_t* __restrict__ A, const bf16_t* __restrict__ Bw,
    const float* __restrict__ r, const float* __restrict__ wa2p,
    float* __restrict__ scoresP)
{
    __shared__ __align__(16) bf16_t aA[128 * 32];
    __shared__ __align__(16) bf16_t wB[128 * 32];
    int tid = threadIdx.x, wave = tid >> 6, lane = tid & 63;
    int m0 = blockIdx.x * 128, n0 = blockIdx.y * 128;
    int srow = lane >> 2, scol = (lane & 3) * 8;
    const bf16_t* Ag = A + (size_t)(m0 + wave * 32 + srow) * 1024 + scol;
    const bf16_t* Bg = Bw + (size_t)(n0 + wave * 32 + srow) * 1024 + scol;
    bf16_t* aL0 = &aA[wave * 1024];
    bf16_t* aL1 = &aA[wave * 1024 + 512];
    bf16_t* bL0 = &wB[wave * 1024];
    bf16_t* bL1 = &wB[wave * 1024 + 512];
    int mw = (wave >> 1) * 64, nw = (wave & 1) * 64;
    f32x4 acc[4][4] = {};
    for (int k0 = 0; k0 < 1024; k0 += 32) {
        gload_lds16(Ag + k0, aL0);
        gload_lds16(Ag + 16 * 1024 + k0, aL1);
        gload_lds16(Bg + k0, bL0);
        gload_lds16(Bg + 16 * 1024 + k0, bL1);
        __syncthreads();
        bf16x8 af[4], bfr[4];
#pragma unroll
        for (int i = 0; i < 4; i++) {
            af[i]  = *(const bf16x8*)(&aA[(mw + i * 16 + (lane & 15)) * 32 + (lane >> 4) * 8]);
            bfr[i] = *(const bf16x8*)(&wB[(nw + i * 16 + (lane & 15)) * 32 + (lane >> 4) * 8]);
        }
#pragma unroll
        for (int mi = 0; mi < 4; mi++)
#pragma unroll
            for (int nj = 0; nj < 4; nj++)
                acc[mi][nj] = __builtin_amdgcn_mfma_f32_16x16x32_bf16(af[mi], bfr[nj], acc[mi][nj], 0, 0, 0);
        __syncthreads();
    }
    int ncol = lane & 15;
    int part = blockIdx.y * 2 + (wave & 1);
    float w2[4];
#pragma unroll
    for (int nj = 0; nj < 4; nj++) w2[nj] = wa2p[n0 + nw + nj * 16 + ncol];
#pragma unroll
    for (int mi = 0; mi < 4; mi++) {
#pragma unroll
        for (int rg = 0; rg < 4; rg++) {
            int m = m0 + mw + mi * 16 + (lane >> 4) * 4 + rg;
            const float* rrow = r + (size_t)(m & 63) * 1800;
            float s = 0.f;
#pragma unroll
            for (int nj = 0; nj < 4; nj++) {
                int n = n0 + nw + nj * 16 + ncol;
                float rv = (n < 1800) ? rrow[n] : 0.f;
                s += fmaxf(acc[mi][nj][rg] + rv, 0.f) * w2[nj];
            }
#pragma unroll
            for (int d = 1; d < 16; d <<= 1) s += __shfl_xor(s, d, 64);
            if (ncol == 0) scoresP[(size_t)part * 12544 + m] = s;
        }
    }
}

// ---------------- softmax over S (per b) + beta gate ----------------
__global__ __launch_bounds__(256) void softmax_beta(
    const float* __restrict__ scoresP, float* __restrict__ aw32,
    float* __restrict__ aw_out, const bf16_t* __restrict__ h0,
    const float* __restrict__ Wb, const float* __restrict__ bb,
    const float* __restrict__ ba2, float* __restrict__ beta)
{
    int b = blockIdx.x, t = threadIdx.x;
    __shared__ float red[4];
    __shared__ float bc;
    float v = -1e30f;
    if (t < 196) {
        float s = ba2[0];
        for (int p = 0; p < 30; p++) s += scoresP[(size_t)p * 12544 + t * 64 + b];
        v = s;
    }
    float m = v;
    for (int d = 1; d < 64; d <<= 1) m = fmaxf(m, __shfl_xor(m, d, 64));
    if ((t & 63) == 0) red[t >> 6] = m;
    __syncthreads();
    if (t == 0) bc = fmaxf(fmaxf(red[0], red[1]), fmaxf(red[2], red[3]));
    __syncthreads();
    m = bc;
    float e = (t < 196) ? expf(v - m) : 0.f;
    float s = e;
    for (int d = 1; d < 64; d <<= 1) s += __shfl_xor(s, d, 64);
    __syncthreads();
    if ((t & 63) == 0) red[t >> 6] = s;
    __syncthreads();
    if (t == 0) bc = red[0] + red[1] + red[2] + red[3];
    __syncthreads();
    float inv = 1.f / bc;
    if (t < 196) { float a = e * inv; aw32[t * 64 + b] = a; aw_out[t * 64 + b] = a; }
    float bs = 0.f;
    for (int k = t; k < 1800; k += 256) bs += (float)h0[b * 1800 + k] * Wb[k];
    for (int d = 1; d < 64; d <<= 1) bs += __shfl_xor(bs, d, 64);
    __syncthreads();
    if ((t & 63) == 0) red[t >> 6] = bs;
    __syncthreads();
    if (t == 0) beta[b] = 1.f / (1.f + expf(-(red[0] + red[1] + red[2] + red[3] + bb[0])));
}

// ---------------- ctx = (sum_s aw*h) * beta -> xA[:,512:], zA[:,2312:] ----------------
__global__ void ctx_kernel(const bf16_t* __restrict__ h_bf, const float* __restrict__ aw32,
                           const float* __restrict__ beta, bf16_t* __restrict__ xA, bf16_t* __restrict__ zA) {
    int idx = blockIdx.x * 256 + threadIdx.x;    // 65536 = B*E
    int b = idx >> 10, e = idx & 1023;
    float s = 0.f;
    for (int si = 0; si < 196; si++) s += aw32[si * 64 + b] * (float)h_bf[(size_t)si * 65536 + idx];
    float c = s * beta[b];
    xA[b * 1536 + 512 + e] = (bf16_t)c;
    zA[b * 3336 + 2312 + e] = (bf16_t)c;
}

// ---------------- gathers: emb[E_tm1] -> xA[:,0:512]; emb[argmax] -> zA[:,1800:2312] ----------------
__global__ void gather_kernel(const float* __restrict__ emb, const int* __restrict__ E_tm1,
                              const int* __restrict__ amax, bf16_t* __restrict__ xA, bf16_t* __restrict__ zA) {
    int idx = blockIdx.x * 256 + threadIdx.x;    // 65536 = 2*64*512
    int half = idx >> 15;
    int j = idx & 32767; int b = j >> 9, w = j & 511;
    if (half == 0) xA[b * 1536 + w] = (bf16_t)emb[(size_t)E_tm1[b] * 512 + w];
    else           zA[b * 3336 + 1800 + w] = (bf16_t)emb[(size_t)amax[b] * 512 + w];
}

// ---------------- LSTM elementwise: sums 4 gate partial slices + both biases ----------------
__global__ void lstm_kernel(const float* __restrict__ gatesP, const float* __restrict__ c0,
                            const float* __restrict__ b_ih, const float* __restrict__ b_hh,
                            float* __restrict__ oh, float* __restrict__ oc, bf16_t* __restrict__ zA) {
    int idx = blockIdx.x * 256 + threadIdx.x;    // 115200 = B*D
    if (idx >= 115200) return;
    int b = idx / 1800, d = idx - b * 1800;
    const float* g0 = gatesP + (size_t)b * 7200;
    float gv[4];
#pragma unroll
    for (int gi = 0; gi < 4; gi++) {
        int col = gi * 1800 + d;
        float s = b_ih[col] + b_hh[col];
#pragma unroll
        for (int p = 0; p < 4; p++) s += g0[(size_t)p * 460800 + col];
        gv[gi] = s;
    }
    float ig = 1.f / (1.f + expf(-gv[0]));
    float fg = 1.f / (1.f + expf(-gv[1]));
    float gg = tanhf(gv[2]);
    float og = 1.f / (1.f + expf(-gv[3]));
    float ct = fg * c0[idx] + ig * gg;
    float ht = og * tanhf(ct);
    oh[idx] = ht;
    oc[idx] = ct;
    zA[b * 3336 + d] = (bf16_t)ht;
}

extern "C" void kernel_launch(void* const* d_in, const int* in_sizes, int n_in,
                              void* d_out, int out_size, void* d_ws, size_t ws_size,
                              hipStream_t stream) {
    const int*   E_tm1 = (const int*)d_in[0];
    const float* y_tm1 = (const float*)d_in[1];
    const float* h     = (const float*)d_in[2];
    const float* emb   = (const float*)d_in[3];
    const float* W_ih  = (const float*)d_in[4];
    const float* b_ih  = (const float*)d_in[5];
    const float* W_hh  = (const float*)d_in[6];
    const float* b_hh  = (const float*)d_in[7];
    const float* W_out = (const float*)d_in[8];
    const float* b_out = (const float*)d_in[9];
    const float* Wh1   = (const float*)d_in[10];
    const float* bh1   = (const float*)d_in[11];
    const float* Wh2   = (const float*)d_in[12];
    const float* bh2   = (const float*)d_in[13];
    const float* Wc1   = (const float*)d_in[14];
    const float* bc1   = (const float*)d_in[15];
    const float* Wc2   = (const float*)d_in[16];
    const float* bc2   = (const float*)d_in[17];
    const float* Wa1   = (const float*)d_in[18];
    const float* ba1   = (const float*)d_in[19];
    const float* Wa2   = (const float*)d_in[20];
    const float* ba2   = (const float*)d_in[21];
    const float* Wb    = (const float*)d_in[22];
    const float* bb    = (const float*)d_in[23];

    // workspace layout (fp32 elements)
    float* wsf      = (float*)d_ws;
    float* bigpart  = wsf;                    // 6,144,000 floats: shared (serially) by
    float* gates    = bigpart;                //  - small-chain partials [8][64][1800]
                                              //  - gate partials        [4][64][7200]
                                              //  - logits partials      [3][64][32000]
    float* r_buf    = wsf + 6144000;          // 115200
    float* scoresP  = wsf + 6259200;          // 376320 ([30][12544])
    float* aw32     = wsf + 6635520;          // 12544
    float* beta     = wsf + 6648064;          // 64
    float* c0       = wsf + 6648128;          // 115200
    float* wa2p     = wsf + 6763328;          // 1920
    int*   amax     = (int*)(wsf + 6765248);  // 64
    bf16_t* havg = (bf16_t*)(wsf + 6765312);  // 65536 bf16
    bf16_t* t1   = havg + 65536;              // 115200
    bf16_t* t2   = t1 + 115200;               // 115200
    bf16_t* h0   = t2 + 115200;               // 115200
    bf16_t* xA   = h0 + 115200;               // 64*1536
    bf16_t* zA   = xA + 98304;                // 64*3336 = 213504
    bf16_t* h_bf = zA + 213504;               // 196*64*1024 = 12845056
    bf16_t* Wa1bf= h_bf + 12845056;           // 1920*1024 = 1966080

    float* out        = (float*)d_out;
    float* out_logits = out;                  // 64*32000
    float* out_ht     = out + 2048000;        // 64*1800
    float* out_ct     = out + 2163200;        // 64*1800
    float* out_aw     = out + 2278400;        // 196*64

    mean_kernel<<<256, 256, 0, stream>>>(h, havg, h_bf);
    conv_wa1<<<7680, 256, 0, stream>>>(Wa1, Wa2, Wa1bf, wa2p);
    argmax_kernel<<<64, 256, 0, stream>>>(y_tm1, amax);

    // t1 = relu(havg @ Wh1^T + bh1)
    gemm64v2<<<dim3(29, 8), 256, 0, stream>>>(havg, 1024, 1024, Wh1, 1024, bigpart, 1800, 1800);
    gemm_finalize<<<450, 256, 0, stream>>>(bigpart, 8, bh1, 1, nullptr, t1, 1800);
    // t2 = relu(havg @ Wc1^T + bc1)
    gemm64v2<<<dim3(29, 8), 256, 0, stream>>>(havg, 1024, 1024, Wc1, 1024, bigpart, 1800, 1800);
    gemm_finalize<<<450, 256, 0, stream>>>(bigpart, 8, bc1, 1, nullptr, t2, 1800);
    // h0 = t1 @ Wh2^T + bh2
    gemm64v2<<<dim3(29, 8), 256, 0, stream>>>(t1, 1800, 1800, Wh2, 1800, bigpart, 1800, 1800);
    gemm_finalize<<<450, 256, 0, stream>>>(bigpart, 8, bh2, 0, nullptr, h0, 1800);
    // c0 = t2 @ Wc2^T + bc2
    gemm64v2<<<dim3(29, 8), 256, 0, stream>>>(t2, 1800, 1800, Wc2, 1800, bigpart, 1800, 1800);
    gemm_finalize<<<450, 256, 0, stream>>>(bigpart, 8, bc2, 0, c0, nullptr, 1800);
    // r = h0 @ Wa1[:, :1800]^T + ba1
    gemm64v2<<<dim3(29, 8), 256, 0, stream>>>(h0, 1800, 1800, Wa1, 2824, bigpart, 1800, 1800);
    gemm_finalize<<<450, 256, 0, stream>>>(bigpart, 8, ba1, 0, r_buf, nullptr, 1800);

    // fused attention scores: 128x128-tile GEMM over M=12544, N=1920(pad), K=1024
    attn_gemm<<<dim3(98, 15), 256, 0, stream>>>(h_bf, Wa1bf, r_buf, wa2p, scoresP);
    softmax_beta<<<64, 256, 0, stream>>>(scoresP, aw32, out_aw, h0, Wb, bb, ba2, beta);
    ctx_kernel<<<256, 256, 0, stream>>>(h_bf, aw32, beta, xA, zA);
    gather_kernel<<<256, 256, 0, stream>>>(emb, E_tm1, amax, xA, zA);

    // LSTM gates: two split-K GEMMs write 4 partial slices; lstm_kernel sums + biases
    gemm64v2<<<dim3(113, 2), 256, 0, stream>>>(xA, 1536, 1536, W_ih, 1536, gates, 7200, 7200);
    gemm64v2<<<dim3(113, 2), 256, 0, stream>>>(h0, 1800, 1800, W_hh, 1800, gates + 2 * 460800, 7200, 7200);
    lstm_kernel<<<450, 256, 0, stream>>>(gates, c0, b_ih, b_hh, out_ht, out_ct, zA);

    // logits = zA @ W_out^T + b_out (BW-bound: 427 MB fp32 W_out; split-K x3 for occupancy)
    gemm64v2<<<dim3(500, 3), 256, 0, stream>>>(zA, 3336, 3336, W_out, 3336, bigpart, 32000, 32000);
    gemm_finalize<<<8000, 256, 0, stream>>>(bigpart, 3, b_out, 0, out_logits, nullptr, 32000);
}